// Round 9
// baseline (1269.490 us; speedup 1.0000x reference)
//
#include <hip/hip_runtime.h>
#include <hip/hip_bf16.h>

#define NODES 50000
#define EDGES 800000
#define DIN   19
#define LAYERS 3
#define BN_EPS 1e-5f

#define NBINS 196          // ceil(NODES/256), bin = dst>>8
#define EPB   4096         // edges per sort chunk
#define NBLK  196          // ceil(EDGES/EPB)
#define NTILES 782         // ceil(NODES/64)
#define TPB   256

typedef __attribute__((ext_vector_type(4))) float f32x4;
typedef __attribute__((ext_vector_type(2))) float f32x2;
typedef __attribute__((ext_vector_type(8))) short s16x8;

__device__ inline ushort bf16bits(float f) {
    __hip_bfloat16 h = __float2bfloat16(f);
    return *reinterpret_cast<ushort*>(&h);
}

// ---------- fp8 pack/unpack (e4m3 via HW cvt; e5m2-from-f16 fallback, header-free) ----------
#if __has_builtin(__builtin_amdgcn_cvt_pk_f32_fp8) && __has_builtin(__builtin_amdgcn_cvt_pk_fp8_f32)
__device__ inline unsigned pack4_fp8(float a, float b, float c, float d) {
    unsigned w = __builtin_amdgcn_cvt_pk_fp8_f32(a, b, 0u, false);
    return __builtin_amdgcn_cvt_pk_fp8_f32(c, d, w, true);
}
__device__ inline float dec_byte_fp8(unsigned byte) {   // bits[7:0] -> float
    f32x2 lo = __builtin_amdgcn_cvt_pk_f32_fp8(byte, false);
    return lo.x;
}
#else
__device__ inline unsigned enc1(float f) {            // e5m2 = top byte of fp16, RN
    _Float16 hf = (_Float16)f;
    unsigned u = (unsigned)*reinterpret_cast<unsigned short*>(&hf);
    u = (u + 0x7Fu + ((u >> 8) & 1u)) >> 8;
    return u & 0xFFu;
}
__device__ inline float dec_byte_fp8(unsigned b) {
    unsigned short u = (unsigned short)(b << 8);
    _Float16 hf = *reinterpret_cast<_Float16*>(&u);
    return (float)hf;
}
__device__ inline unsigned pack4_fp8(float a, float b, float c, float d) {
    return enc1(a) | (enc1(b) << 8) | (enc1(c) << 16) | (enc1(d) << 24);
}
#endif

// ---------------- prep: zero stats, build transposed bf16 weights ----------------

__global__ void k_wprep(const float* __restrict__ w_in, const float* __restrict__ wl,
                        const float* __restrict__ wr, ushort* __restrict__ WiT,
                        ushort* __restrict__ WcatT, float* __restrict__ stats) {
    int i0 = blockIdx.x * blockDim.x + threadIdx.x;
    int stride = gridDim.x * blockDim.x;
    for (int i = i0; i < 4 * 2048; i += stride) stats[i] = 0.0f;
    for (int i = i0; i < 64 * 32; i += stride) {
        int c = i >> 5, k = i & 31;
        WiT[i] = bf16bits(k < DIN ? w_in[k * 64 + c] : 0.0f);
    }
    for (int i = i0; i < LAYERS * 64 * 128; i += stride) {
        int l = i >> 13, rem = i & 8191;
        int c = rem >> 7, k = rem & 127;
        float v = (k < 64) ? wl[(l * 64 + k) * 64 + c] : wr[(l * 64 + (k - 64)) * 64 + c];
        WcatT[i] = bf16bits(v);
    }
}

// ---------------- pass A: per-block LDS counting sort of edges by dst>>8 ----------------
// bbuf entry = (dst&255)<<24 | src;  cb[bin*NBLK+blk] = (offset within chunk, count)

__global__ __launch_bounds__(1024) void k_sortA(const int* __restrict__ src, const int* __restrict__ dst,
                                                int2* __restrict__ cb, unsigned* __restrict__ bbuf) {
    __shared__ int hist[256];
    __shared__ int cur[256];
    __shared__ int wsum4[4];
    __shared__ unsigned stage[EPB];
    int blk = blockIdx.x, t = threadIdx.x;
    int e0 = blk * EPB;
    int ne = min(EPB, EDGES - e0);
    int d[4]; unsigned pk[4];
    #pragma unroll
    for (int i = 0; i < 4; ++i) {
        int j = t + i * 1024;
        if (j < ne) {
            int dd = dst[e0 + j];
            d[i] = dd;
            pk[i] = ((unsigned)(dd & 255) << 24) | (unsigned)src[e0 + j];
        } else d[i] = -1;
    }
    if (t < 256) hist[t] = 0;
    __syncthreads();
    #pragma unroll
    for (int i = 0; i < 4; ++i)
        if (d[i] >= 0) atomicAdd(&hist[d[i] >> 8], 1);
    __syncthreads();
    int ln = t & 63, wv = t >> 6;
    int cntv = 0, inc = 0;
    if (t < 256) {
        cntv = hist[t];
        inc = cntv;
        #pragma unroll
        for (int s = 1; s < 64; s <<= 1) {
            int u = __shfl_up(inc, s);
            if (ln >= s) inc += u;
        }
        if (ln == 63) wsum4[wv] = inc;
    }
    __syncthreads();
    if (t < 256) {
        int woff = 0;
        #pragma unroll
        for (int i = 0; i < 4; ++i) if (i < wv) woff += wsum4[i];
        int excl = woff + inc - cntv;
        cur[t] = excl;
        if (t < NBINS) cb[t * NBLK + blk] = make_int2(excl, cntv);
    }
    __syncthreads();
    #pragma unroll
    for (int i = 0; i < 4; ++i)
        if (d[i] >= 0) {
            int slot = atomicAdd(&cur[d[i] >> 8], 1);
            stage[slot] = pk[i];
        }
    __syncthreads();
    #pragma unroll
    for (int i = 0; i < 4; ++i) {
        int j = t + i * 1024;
        if (j < ne) bbuf[e0 + j] = stage[j];
    }
}

// ---------------- push-mode aggregation: one block per bin, LDS fp32 accumulators ----------------
// lane = feature (64 lanes per edge); gather = one coalesced 64B row; LDS atomic 2-way banked.

__global__ __launch_bounds__(1024) void k_aggbin(const int2* __restrict__ cb,
                                                 const unsigned* __restrict__ bbuf,
                                                 const unsigned* __restrict__ hb8,
                                                 ushort* __restrict__ ABh) {
    __shared__ float acc[256][64];
    __shared__ int ldeg[256];
    __shared__ int soff[NBLK], scnt[NBLK];
    int b = blockIdx.x, t = threadIdx.x;
    float* accf = (float*)acc;
    for (int i = t; i < 256 * 64; i += 1024) accf[i] = 0.0f;
    if (t < 256) ldeg[t] = 0;
    if (t < NBLK) {
        int2 c = cb[b * NBLK + t];
        soff[t] = c.x; scnt[t] = c.y;
    }
    __syncthreads();
    int wv = t >> 6, ln = t & 63;
    int word = ln >> 2, bsh = (ln & 3) * 8;
    for (int sg = wv; sg < NBLK; sg += 16) {
        int cnt = scnt[sg];
        const unsigned* bp = bbuf + sg * EPB + soff[sg];
        int e = 0;
        for (; e + 3 < cnt; e += 4) {
            unsigned q0 = bp[e], q1 = bp[e + 1], q2 = bp[e + 2], q3 = bp[e + 3];
            unsigned w0 = hb8[(size_t)(q0 & 0xFFFFFFu) * 16 + word];
            unsigned w1 = hb8[(size_t)(q1 & 0xFFFFFFu) * 16 + word];
            unsigned w2 = hb8[(size_t)(q2 & 0xFFFFFFu) * 16 + word];
            unsigned w3 = hb8[(size_t)(q3 & 0xFFFFFFu) * 16 + word];
            atomicAdd(&acc[q0 >> 24][ln], dec_byte_fp8((w0 >> bsh) & 0xFFu));
            atomicAdd(&acc[q1 >> 24][ln], dec_byte_fp8((w1 >> bsh) & 0xFFu));
            atomicAdd(&acc[q2 >> 24][ln], dec_byte_fp8((w2 >> bsh) & 0xFFu));
            atomicAdd(&acc[q3 >> 24][ln], dec_byte_fp8((w3 >> bsh) & 0xFFu));
            if (ln == 0) {
                atomicAdd(&ldeg[q0 >> 24], 1); atomicAdd(&ldeg[q1 >> 24], 1);
                atomicAdd(&ldeg[q2 >> 24], 1); atomicAdd(&ldeg[q3 >> 24], 1);
            }
        }
        for (; e < cnt; ++e) {
            unsigned q = bp[e];
            unsigned w = hb8[(size_t)(q & 0xFFFFFFu) * 16 + word];
            atomicAdd(&acc[q >> 24][ln], dec_byte_fp8((w >> bsh) & 0xFFu));
            if (ln == 0) atomicAdd(&ldeg[q >> 24], 1);
        }
    }
    __syncthreads();
    unsigned* AB = (unsigned*)ABh;            // rows = 64 uints (2 bf16 each)
    int nbase = b << 8;
    int nmax = min(256, NODES - nbase);
    for (int i = t; i < nmax * 32; i += 1024) {
        int n = i >> 5, k = i & 31;
        float rd = 1.0f / fmaxf((float)ldeg[n], 1.0f);
        unsigned o = (unsigned)bf16bits(acc[n][2 * k] * rd)
                   | ((unsigned)bf16bits(acc[n][2 * k + 1] * rd) << 16);
        AB[(size_t)(nbase + n) * 64 + k] = o;
    }
}

// ---------------- shared GEMM epilogue: bias + bf16 store + fused BN stats ----------------

__device__ inline void gemm_epilogue(int t, int row0, f32x4* acc, const float* __restrict__ bias,
                                     ushort* __restrict__ tb, float* __restrict__ stats,
                                     float (*red)[128]) {
    int lane = t & 63, wave = t >> 6;
    int r = lane & 15, g = lane >> 4;
    float s_[4], q_[4];
    #pragma unroll
    for (int j = 0; j < 4; ++j) {
        float b = bias[j * 16 + r];
        float s = 0.0f, q = 0.0f;
        #pragma unroll
        for (int i = 0; i < 4; ++i) {
            int row = row0 + wave * 16 + g * 4 + i;
            if (row < NODES) {
                float v = acc[j][i] + b;
                tb[(size_t)row * 64 + j * 16 + r] = bf16bits(v);
                s += v; q += v * v;
            }
        }
        s += __shfl_xor(s, 16); s += __shfl_xor(s, 32);
        q += __shfl_xor(q, 16); q += __shfl_xor(q, 32);
        s_[j] = s; q_[j] = q;
    }
    if (g == 0) {
        #pragma unroll
        for (int j = 0; j < 4; ++j) {
            red[wave][j * 16 + r] = s_[j];
            red[wave][64 + j * 16 + r] = q_[j];
        }
    }
    __syncthreads();
    if (t < 128) {
        float tot = red[0][t] + red[1][t] + red[2][t] + red[3][t];
        atomicAdd(&stats[t * 16], tot);
    }
}

// ---------------- input-proj GEMM: stages x (fp32) -> bf16 LDS tile, K=32 ----------------

__global__ __launch_bounds__(TPB) void k_gemm0(const float* __restrict__ x, const ushort* __restrict__ WiT,
                                               const float* __restrict__ bias, ushort* __restrict__ tb,
                                               float* __restrict__ stats) {
    __shared__ ushort xt[64][40];
    __shared__ float red[4][128];
    int t = threadIdx.x, rb = blockIdx.x;
    int row0 = rb * 64;
    int nv = min(64, NODES - row0);
    unsigned* xz = (unsigned*)xt;
    for (int i = t; i < 64 * 20; i += TPB) xz[i] = 0;
    __syncthreads();
    const float* xs = x + (size_t)row0 * DIN;
    for (int e = t; e < nv * DIN; e += TPB) {
        int n = e / DIN, k = e - n * DIN;
        xt[n][k] = bf16bits(xs[e]);
    }
    __syncthreads();
    int lane = t & 63, wave = t >> 6;
    int r = lane & 15, g = lane >> 4;
    f32x4 acc[4] = {{0.f,0.f,0.f,0.f},{0.f,0.f,0.f,0.f},{0.f,0.f,0.f,0.f},{0.f,0.f,0.f,0.f}};
    s16x8 af = *(const s16x8*)&xt[wave * 16 + r][g * 8];
    #pragma unroll
    for (int j = 0; j < 4; ++j) {
        s16x8 bf = *(const s16x8*)(WiT + (size_t)(j * 16 + r) * 32 + g * 8);
        acc[j] = __builtin_amdgcn_mfma_f32_16x16x32_bf16(af, bf, acc[j], 0, 0, 0);
    }
    gemm_epilogue(t, row0, acc, bias, tb, stats, red);
}

// ---------------- layer GEMM: A = AB[n][128] ([agg|h] bf16), W = WcatT ----------------

__global__ __launch_bounds__(TPB) void k_gemm(const ushort* __restrict__ AB, const ushort* __restrict__ WT,
                                              const float* __restrict__ bias, ushort* __restrict__ tb,
                                              float* __restrict__ stats) {
    __shared__ float red[4][128];
    int t = threadIdx.x;
    int lane = t & 63, wave = t >> 6;
    int row0 = blockIdx.x * 64;
    int r = lane & 15, g = lane >> 4;
    f32x4 acc[4] = {{0.f,0.f,0.f,0.f},{0.f,0.f,0.f,0.f},{0.f,0.f,0.f,0.f},{0.f,0.f,0.f,0.f}};
    int ar = row0 + wave * 16 + r;
    if (ar >= NODES) ar = NODES - 1;
    #pragma unroll
    for (int k0 = 0; k0 < 128; k0 += 32) {
        s16x8 af = *(const s16x8*)(AB + (size_t)ar * 128 + k0 + g * 8);
        #pragma unroll
        for (int j = 0; j < 4; ++j) {
            s16x8 bf = *(const s16x8*)(WT + (size_t)(j * 16 + r) * 128 + k0 + g * 8);
            acc[j] = __builtin_amdgcn_mfma_f32_16x16x32_bf16(af, bf, acc[j], 0, 0, 0);
        }
    }
    gemm_epilogue(t, row0, acc, bias, tb, stats, red);
}

// ---------------- BN finalize + ReLU (+residual); writes h, AB right half, fp8 table ----------------

__global__ void k_apply(const ushort* __restrict__ tb, const float* __restrict__ stats,
                        const float* __restrict__ gamma, const float* __restrict__ beta,
                        float* __restrict__ h, ushort* __restrict__ AB,
                        unsigned* __restrict__ hb8, int residual, int write_next) {
    int idx0 = blockIdx.x * blockDim.x + threadIdx.x;
    int stride = gridDim.x * blockDim.x;
    const float invN = 1.0f / NODES;
    for (int idx = idx0; idx < NODES * 16; idx += stride) {
        int n = idx >> 4;
        int j = (idx & 15) * 4;
        ushort4 tv = *(const ushort4*)(tb + (size_t)n * 64 + j);
        float tf[4] = { __uint_as_float((unsigned)tv.x << 16), __uint_as_float((unsigned)tv.y << 16),
                        __uint_as_float((unsigned)tv.z << 16), __uint_as_float((unsigned)tv.w << 16) };
        f32x4 hv;
        if (residual) hv = *(const f32x4*)(h + (size_t)n * 64 + j);
        float out[4];
        ushort ub[4];
        #pragma unroll
        for (int k = 0; k < 4; ++k) {
            int f = j + k;
            float mu = stats[f * 16] * invN;
            float var = stats[(64 + f) * 16] * invN - mu * mu;
            float sc = gamma[f] * rsqrtf(var + BN_EPS);
            float sh = beta[f] - mu * sc;
            float v = fmaxf(tf[k] * sc + sh, 0.0f);
            out[k] = residual ? (hv[k] + v) : v;
            ub[k] = bf16bits(out[k]);
        }
        *(f32x4*)(h + (size_t)n * 64 + j) = f32x4{out[0], out[1], out[2], out[3]};
        if (write_next) {
            *(ushort4*)(AB + (size_t)n * 128 + 64 + j) = make_ushort4(ub[0], ub[1], ub[2], ub[3]);
            hb8[(size_t)n * 16 + (idx & 15)] = pack4_fp8(out[0], out[1], out[2], out[3]);
        }
    }
}

// ---------------- launch ----------------

extern "C" void kernel_launch(void* const* d_in, const int* in_sizes, int n_in,
                              void* d_out, int out_size, void* d_ws, size_t ws_size,
                              hipStream_t stream) {
    const float* x    = (const float*)d_in[0];
    const int*   ei   = (const int*)d_in[1];
    const float* w_in = (const float*)d_in[2];
    const float* b_in = (const float*)d_in[3];
    const float* bn0g = (const float*)d_in[4];
    const float* bn0b = (const float*)d_in[5];
    const float* wl   = (const float*)d_in[6];
    const float* bl   = (const float*)d_in[7];
    const float* wr   = (const float*)d_in[8];
    const float* bng  = (const float*)d_in[9];
    const float* bnb  = (const float*)d_in[10];
    const int* esrc = ei;
    const int* edst = ei + EDGES;
    float* h = (float*)d_out;

    char* p = (char*)d_ws;
    auto alloc = [&](size_t bytes) {
        char* r = p;
        p += (bytes + 255) & ~size_t(255);
        return r;
    };
    float*    stats  = (float*)alloc((size_t)4 * 2048 * 4);
    int2*     cb     = (int2*)alloc((size_t)NBINS * NBLK * 8);
    unsigned* bbuf   = (unsigned*)alloc((size_t)NBLK * EPB * 4);
    ushort*   WiT    = (ushort*)alloc(64 * 32 * 2);
    ushort*   WcatT  = (ushort*)alloc(LAYERS * 64 * 128 * 2);
    ushort*   tb     = (ushort*)alloc((size_t)NODES * 64 * 2);
    ushort*   AB     = (ushort*)alloc((size_t)NODES * 128 * 2);
    unsigned* hb8    = (unsigned*)alloc((size_t)NODES * 16 * 4);

    k_wprep<<<128, TPB, 0, stream>>>(w_in, wl, wr, WiT, WcatT, stats);
    k_sortA<<<NBLK, 1024, 0, stream>>>(esrc, edst, cb, bbuf);

    k_gemm0<<<NTILES, TPB, 0, stream>>>(x, WiT, b_in, tb, stats);
    k_apply<<<2048, TPB, 0, stream>>>(tb, stats, bn0g, bn0b, h, AB, hb8, 0, 1);

    for (int l = 0; l < LAYERS; ++l) {
        k_aggbin<<<NBINS, 1024, 0, stream>>>(cb, bbuf, hb8, AB);
        k_gemm<<<NTILES, TPB, 0, stream>>>(AB, WcatT + l * 8192, bl + l * 64,
                                           tb, stats + (l + 1) * 2048);
        k_apply<<<2048, TPB, 0, stream>>>(tb, stats + (l + 1) * 2048, bng + l * 64, bnb + l * 64,
                                          h, AB, hb8, 1, l < LAYERS - 1 ? 1 : 0);
    }
}

// Round 10
// 279.055 us; speedup vs baseline: 4.5492x; 4.5492x over previous
//
#include <hip/hip_runtime.h>
#include <hip/hip_bf16.h>

#define NODES 50000
#define EDGES 800000
#define DIN   19
#define LAYERS 3
#define BN_EPS 1e-5f

#define NBINS 196          // ceil(NODES/256), bin = dst>>8
#define EPB   4096         // edges per sort chunk
#define NBLK  196          // ceil(EDGES/EPB)
#define NTILES 782         // ceil(NODES/64)
#define G0TILES 196        // gemm0: 256-row tiles
#define APPLY_BLOCKS 2048
#define TPB   256

typedef __attribute__((ext_vector_type(4))) float f32x4;
typedef __attribute__((ext_vector_type(2))) float f32x2;
typedef __attribute__((ext_vector_type(8))) short s16x8;

__device__ inline ushort bf16bits(float f) {
    __hip_bfloat16 h = __float2bfloat16(f);
    return *reinterpret_cast<ushort*>(&h);
}

// ---------- fp8 pack/unpack (e4m3 via HW cvt; e5m2-from-f16 fallback, header-free) ----------
#if __has_builtin(__builtin_amdgcn_cvt_pk_f32_fp8) && __has_builtin(__builtin_amdgcn_cvt_pk_fp8_f32)
__device__ inline unsigned pack4_fp8(float a, float b, float c, float d) {
    unsigned w = __builtin_amdgcn_cvt_pk_fp8_f32(a, b, 0u, false);
    return __builtin_amdgcn_cvt_pk_fp8_f32(c, d, w, true);
}
__device__ inline void acc4_fp8(unsigned v, float& a0, float& a1, float& a2, float& a3) {
    f32x2 lo = __builtin_amdgcn_cvt_pk_f32_fp8(v, false);
    f32x2 hi = __builtin_amdgcn_cvt_pk_f32_fp8(v, true);
    a0 += lo.x; a1 += lo.y; a2 += hi.x; a3 += hi.y;
}
#else
__device__ inline unsigned enc1(float f) {            // e5m2 = top byte of fp16, RN
    _Float16 hf = (_Float16)f;
    unsigned u = (unsigned)*reinterpret_cast<unsigned short*>(&hf);
    u = (u + 0x7Fu + ((u >> 8) & 1u)) >> 8;
    return u & 0xFFu;
}
__device__ inline float dec1(unsigned b) {
    unsigned short u = (unsigned short)(b << 8);
    _Float16 hf = *reinterpret_cast<_Float16*>(&u);
    return (float)hf;
}
__device__ inline unsigned pack4_fp8(float a, float b, float c, float d) {
    return enc1(a) | (enc1(b) << 8) | (enc1(c) << 16) | (enc1(d) << 24);
}
__device__ inline void acc4_fp8(unsigned v, float& a0, float& a1, float& a2, float& a3) {
    a0 += dec1(v & 0xFF); a1 += dec1((v >> 8) & 0xFF);
    a2 += dec1((v >> 16) & 0xFF); a3 += dec1(v >> 24);
}
#endif

// ---------------- k_prep: zero bintot/stats, build transposed bf16 weights ----------------

__global__ void k_prep(const float* __restrict__ w_in, const float* __restrict__ wl,
                       const float* __restrict__ wr, ushort* __restrict__ WiT,
                       ushort* __restrict__ WcatT, int* __restrict__ bintot,
                       float* __restrict__ stats) {
    int i0 = blockIdx.x * blockDim.x + threadIdx.x;
    int stride = gridDim.x * blockDim.x;
    for (int i = i0; i < NBINS; i += stride) bintot[i] = 0;
    for (int i = i0; i < 4 * 2048; i += stride) stats[i] = 0.0f;
    for (int i = i0; i < 64 * 32; i += stride) {
        int c = i >> 5, k = i & 31;
        WiT[i] = bf16bits(k < DIN ? w_in[k * 64 + c] : 0.0f);
    }
    for (int i = i0; i < LAYERS * 64 * 128; i += stride) {
        int l = i >> 13, rem = i & 8191;
        int c = rem >> 7, k = rem & 127;
        float v = (k < 64) ? wl[(l * 64 + k) * 64 + c] : wr[(l * 64 + (k - 64)) * 64 + c];
        WcatT[i] = bf16bits(v);
    }
}

// ================= K2: edge counting-sort (blocks 0..NBLK-1)  ∥  input-proj GEMM =================

union SMemK2 {
    struct { int hist[256], cur[256], wsum[4]; unsigned stage[EPB]; } sort;    // ~18.4 KB
    struct { ushort xt[256][40]; float red[4][4][128]; } g0;                   // ~28.7 KB
};

__device__ inline void do_sortA(int blk, int t, const int* __restrict__ src,
                                const int* __restrict__ dst, int2* __restrict__ cb,
                                int* __restrict__ bintot, unsigned* __restrict__ bbuf,
                                SMemK2& sm) {
    int e0 = blk * EPB;
    int ne = min(EPB, EDGES - e0);
    int d[4]; unsigned pk[4];
    #pragma unroll
    for (int i = 0; i < 4; ++i) {
        int j = t + i * 1024;
        if (j < ne) {
            int dd = dst[e0 + j];
            d[i] = dd;
            pk[i] = ((unsigned)(dd & 255) << 24) | (unsigned)src[e0 + j];
        } else d[i] = -1;
    }
    if (t < 256) sm.sort.hist[t] = 0;
    __syncthreads();
    #pragma unroll
    for (int i = 0; i < 4; ++i)
        if (d[i] >= 0) atomicAdd(&sm.sort.hist[d[i] >> 8], 1);
    __syncthreads();
    int ln = t & 63, wv = t >> 6;
    int cntv = 0, inc = 0;
    if (t < 256) {
        cntv = sm.sort.hist[t];
        inc = cntv;
        #pragma unroll
        for (int s = 1; s < 64; s <<= 1) {
            int u = __shfl_up(inc, s);
            if (ln >= s) inc += u;
        }
        if (ln == 63) sm.sort.wsum[wv] = inc;
    }
    __syncthreads();
    if (t < 256) {
        int woff = 0;
        #pragma unroll
        for (int i = 0; i < 4; ++i) if (i < wv) woff += sm.sort.wsum[i];
        int excl = woff + inc - cntv;
        sm.sort.cur[t] = excl;
        if (t < NBINS) {
            cb[t * NBLK + blk] = make_int2(excl, cntv);
            if (cntv) atomicAdd(&bintot[t], cntv);
        }
    }
    __syncthreads();
    #pragma unroll
    for (int i = 0; i < 4; ++i)
        if (d[i] >= 0) {
            int slot = atomicAdd(&sm.sort.cur[d[i] >> 8], 1);
            sm.sort.stage[slot] = pk[i];
        }
    __syncthreads();
    #pragma unroll
    for (int i = 0; i < 4; ++i) {
        int j = t + i * 1024;
        if (j < ne) bbuf[e0 + j] = sm.sort.stage[j];
    }
}

__device__ inline void do_gemm0(int tile, int t, const float* __restrict__ x,
                                const ushort* __restrict__ WiT, const float* __restrict__ bias,
                                ushort* __restrict__ tb, float* __restrict__ stats,
                                SMemK2& sm) {
    int base = tile * 256;
    int nv = min(256, NODES - base);
    unsigned* xz = (unsigned*)sm.g0.xt;
    for (int i = t; i < 256 * 20; i += 1024) xz[i] = 0;
    __syncthreads();
    const float* xs = x + (size_t)base * DIN;
    for (int e = t; e < nv * DIN; e += 1024) {
        int n = e / DIN, k = e - n * DIN;
        sm.g0.xt[n][k] = bf16bits(xs[e]);
    }
    __syncthreads();
    int grp = t >> 8, tl = t & 255;
    int lane = t & 63, wl = (tl >> 6);
    int r = lane & 15, g = lane >> 4;
    f32x4 acc[4] = {{0.f,0.f,0.f,0.f},{0.f,0.f,0.f,0.f},{0.f,0.f,0.f,0.f},{0.f,0.f,0.f,0.f}};
    s16x8 af = *(const s16x8*)&sm.g0.xt[grp * 64 + wl * 16 + r][g * 8];
    #pragma unroll
    for (int j = 0; j < 4; ++j) {
        s16x8 bf = *(const s16x8*)(WiT + (size_t)(j * 16 + r) * 32 + g * 8);
        acc[j] = __builtin_amdgcn_mfma_f32_16x16x32_bf16(af, bf, acc[j], 0, 0, 0);
    }
    int row0 = base + grp * 64 + wl * 16;
    float s_[4], q_[4];
    #pragma unroll
    for (int j = 0; j < 4; ++j) {
        float b = bias[j * 16 + r];
        float s = 0.0f, q = 0.0f;
        #pragma unroll
        for (int i = 0; i < 4; ++i) {
            int row = row0 + g * 4 + i;
            if (row < NODES) {
                float v = acc[j][i] + b;
                tb[(size_t)row * 64 + j * 16 + r] = bf16bits(v);
                s += v; q += v * v;
            }
        }
        s += __shfl_xor(s, 16); s += __shfl_xor(s, 32);
        q += __shfl_xor(q, 16); q += __shfl_xor(q, 32);
        s_[j] = s; q_[j] = q;
    }
    if (g == 0) {
        #pragma unroll
        for (int j = 0; j < 4; ++j) {
            sm.g0.red[grp][wl][j * 16 + r] = s_[j];
            sm.g0.red[grp][wl][64 + j * 16 + r] = q_[j];
        }
    }
    __syncthreads();
    if (tl < 128) {
        float tot = sm.g0.red[grp][0][tl] + sm.g0.red[grp][1][tl] +
                    sm.g0.red[grp][2][tl] + sm.g0.red[grp][3][tl];
        atomicAdd(&stats[tl * 16], tot);
    }
}

__global__ __launch_bounds__(1024) void k_sort_g0(const int* __restrict__ esrc, const int* __restrict__ edst,
                                                  int2* __restrict__ cb, int* __restrict__ bintot,
                                                  unsigned* __restrict__ bbuf,
                                                  const float* __restrict__ x, const ushort* __restrict__ WiT,
                                                  const float* __restrict__ bias, ushort* __restrict__ tb,
                                                  float* __restrict__ stats) {
    __shared__ SMemK2 sm;
    int t = threadIdx.x;
    if (blockIdx.x < NBLK) do_sortA(blockIdx.x, t, esrc, edst, cb, bintot, bbuf, sm);
    else                   do_gemm0(blockIdx.x - NBLK, t, x, WiT, bias, tb, stats, sm);
}

// ================= K3: CSR assembly (blocks 0..NBINS-1) ∥ BN-apply layer 0 =================

__device__ inline int ubound(const int* pre, int f) {
    int lo = 0, hi = NBLK;
    while (lo + 1 < hi) {
        int mid = (lo + hi) >> 1;
        if (pre[mid] <= f) lo = mid; else hi = mid;
    }
    return lo;
}

struct SMemBinB {
    int red[256];
    int segoff[NBLK], segcnt[NBLK], pre[NBLK + 1];
    int deg[256], loff[256], cur[256];
    int wsum4[4];
};

__device__ inline void do_binB(int b, int t, const int2* __restrict__ cb,
                               const int* __restrict__ bintot, const unsigned* __restrict__ bbuf,
                               int* __restrict__ off, float* __restrict__ rden,
                               int* __restrict__ ebuf, SMemBinB& sm) {
    int ln = t & 63, wv = t >> 6;
    sm.red[t] = (t < b) ? bintot[t] : 0;
    __syncthreads();
    #pragma unroll
    for (int s = 128; s > 0; s >>= 1) {
        if (t < s) sm.red[t] += sm.red[t + s];
        __syncthreads();
    }
    int binoff = sm.red[0];
    if (t < NBLK) {
        int2 c = cb[b * NBLK + t];
        sm.segoff[t] = c.x; sm.segcnt[t] = c.y;
    }
    sm.deg[t] = 0; sm.cur[t] = 0;
    __syncthreads();
    if (wv == 0) {
        int carry = 0;
        for (int base = 0; base < NBLK; base += 64) {
            int idx = base + ln;
            int v = (idx < NBLK) ? sm.segcnt[idx] : 0;
            int inc = v;
            #pragma unroll
            for (int s = 1; s < 64; s <<= 1) {
                int u = __shfl_up(inc, s);
                if (ln >= s) inc += u;
            }
            if (idx < NBLK) sm.pre[idx] = carry + inc - v;
            carry += __shfl(inc, 63);
        }
        if (ln == 0) sm.pre[NBLK] = carry;
    }
    __syncthreads();
    int total = sm.pre[NBLK];
    for (int f = t; f < total; f += TPB) {
        int sg = ubound(sm.pre, f);
        unsigned e = bbuf[sg * EPB + sm.segoff[sg] + (f - sm.pre[sg])];
        atomicAdd(&sm.deg[e >> 24], 1);
    }
    __syncthreads();
    int dv = sm.deg[t], inc2 = dv;
    #pragma unroll
    for (int s = 1; s < 64; s <<= 1) {
        int u = __shfl_up(inc2, s);
        if (ln >= s) inc2 += u;
    }
    if (ln == 63) sm.wsum4[wv] = inc2;
    __syncthreads();
    int woff = 0;
    #pragma unroll
    for (int i = 0; i < 4; ++i) if (i < wv) woff += sm.wsum4[i];
    int excl = woff + inc2 - dv;
    sm.loff[t] = excl;
    int node = (b << 8) + t;
    if (node < NODES) {
        off[node] = binoff + excl;
        rden[node] = 1.0f / fmaxf((float)dv, 1.0f);
    }
    if (b == NBINS - 1 && t == 0) off[NODES] = EDGES;
    __syncthreads();
    for (int f = t; f < total; f += TPB) {
        int sg = ubound(sm.pre, f);
        unsigned e = bbuf[sg * EPB + sm.segoff[sg] + (f - sm.pre[sg])];
        int dd = e >> 24;
        int slot = atomicAdd(&sm.cur[dd], 1);
        ebuf[binoff + sm.loff[dd] + slot] = (int)(e & 0xFFFFFFu);
    }
}

__device__ inline void do_apply(int idx0, int stride, const ushort* __restrict__ tb,
                                const float* __restrict__ stats, const float* __restrict__ gamma,
                                const float* __restrict__ beta, float* __restrict__ h,
                                ushort* __restrict__ AB, unsigned* __restrict__ hb8,
                                int residual, int write_next) {
    const float invN = 1.0f / NODES;
    for (int idx = idx0; idx < NODES * 16; idx += stride) {
        int n = idx >> 4;
        int j = (idx & 15) * 4;
        ushort4 tv = *(const ushort4*)(tb + (size_t)n * 64 + j);
        float tf[4] = { __uint_as_float((unsigned)tv.x << 16), __uint_as_float((unsigned)tv.y << 16),
                        __uint_as_float((unsigned)tv.z << 16), __uint_as_float((unsigned)tv.w << 16) };
        f32x4 hv;
        if (residual) hv = *(const f32x4*)(h + (size_t)n * 64 + j);
        float out[4];
        ushort ub[4];
        #pragma unroll
        for (int k = 0; k < 4; ++k) {
            int f = j + k;
            float mu = stats[f * 16] * invN;
            float var = stats[(64 + f) * 16] * invN - mu * mu;
            float sc = gamma[f] * rsqrtf(var + BN_EPS);
            float sh = beta[f] - mu * sc;
            float v = fmaxf(tf[k] * sc + sh, 0.0f);
            out[k] = residual ? (hv[k] + v) : v;
            ub[k] = bf16bits(out[k]);
        }
        *(f32x4*)(h + (size_t)n * 64 + j) = f32x4{out[0], out[1], out[2], out[3]};
        if (write_next) {
            *(ushort4*)(AB + (size_t)n * 128 + 64 + j) = make_ushort4(ub[0], ub[1], ub[2], ub[3]);
            hb8[(size_t)n * 16 + (idx & 15)] = pack4_fp8(out[0], out[1], out[2], out[3]);
        }
    }
}

__global__ __launch_bounds__(TPB) void k_csr_bn0(const int2* __restrict__ cb, const int* __restrict__ bintot,
                                                 const unsigned* __restrict__ bbuf,
                                                 int* __restrict__ off, float* __restrict__ rden,
                                                 int* __restrict__ ebuf,
                                                 const ushort* __restrict__ tb, const float* __restrict__ stats,
                                                 const float* __restrict__ gamma, const float* __restrict__ beta,
                                                 float* __restrict__ h, ushort* __restrict__ AB,
                                                 unsigned* __restrict__ hb8) {
    __shared__ SMemBinB sm;
    int t = threadIdx.x;
    if (blockIdx.x < NBINS) {
        do_binB(blockIdx.x, t, cb, bintot, bbuf, off, rden, ebuf, sm);
    } else {
        int vb = blockIdx.x - NBINS;
        do_apply(vb * TPB + t, APPLY_BLOCKS * TPB, tb, stats, gamma, beta, h, AB, hb8, 0, 1);
    }
}

// ---------------- layer GEMM: A = AB[n][128] ([agg|h] bf16), W = WcatT ----------------

__global__ __launch_bounds__(TPB) void k_gemm(const ushort* __restrict__ AB, const ushort* __restrict__ WT,
                                              const float* __restrict__ bias, ushort* __restrict__ tb,
                                              float* __restrict__ stats) {
    __shared__ float red[4][128];
    int t = threadIdx.x;
    int lane = t & 63, wave = t >> 6;
    int row0 = blockIdx.x * 64;
    int r = lane & 15, g = lane >> 4;
    f32x4 acc[4] = {{0.f,0.f,0.f,0.f},{0.f,0.f,0.f,0.f},{0.f,0.f,0.f,0.f},{0.f,0.f,0.f,0.f}};
    int ar = row0 + wave * 16 + r;
    if (ar >= NODES) ar = NODES - 1;
    #pragma unroll
    for (int k0 = 0; k0 < 128; k0 += 32) {
        s16x8 af = *(const s16x8*)(AB + (size_t)ar * 128 + k0 + g * 8);
        #pragma unroll
        for (int j = 0; j < 4; ++j) {
            s16x8 bf = *(const s16x8*)(WT + (size_t)(j * 16 + r) * 128 + k0 + g * 8);
            acc[j] = __builtin_amdgcn_mfma_f32_16x16x32_bf16(af, bf, acc[j], 0, 0, 0);
        }
    }
    float s_[4], q_[4];
    #pragma unroll
    for (int j = 0; j < 4; ++j) {
        float b = bias[j * 16 + r];
        float s = 0.0f, q = 0.0f;
        #pragma unroll
        for (int i = 0; i < 4; ++i) {
            int row = row0 + wave * 16 + g * 4 + i;
            if (row < NODES) {
                float v = acc[j][i] + b;
                tb[(size_t)row * 64 + j * 16 + r] = bf16bits(v);
                s += v; q += v * v;
            }
        }
        s += __shfl_xor(s, 16); s += __shfl_xor(s, 32);
        q += __shfl_xor(q, 16); q += __shfl_xor(q, 32);
        s_[j] = s; q_[j] = q;
    }
    if (g == 0) {
        #pragma unroll
        for (int j = 0; j < 4; ++j) {
            red[wave][j * 16 + r] = s_[j];
            red[wave][64 + j * 16 + r] = q_[j];
        }
    }
    __syncthreads();
    if (t < 128) {
        float tot = red[0][t] + red[1][t] + red[2][t] + red[3][t];
        atomicAdd(&stats[t * 16], tot);
    }
}

// ---------------- BN finalize + ReLU + residual (standalone, layers 1..3) ----------------

__global__ void k_apply(const ushort* __restrict__ tb, const float* __restrict__ stats,
                        const float* __restrict__ gamma, const float* __restrict__ beta,
                        float* __restrict__ h, ushort* __restrict__ AB,
                        unsigned* __restrict__ hb8, int residual, int write_next) {
    do_apply(blockIdx.x * blockDim.x + threadIdx.x, gridDim.x * blockDim.x,
             tb, stats, gamma, beta, h, AB, hb8, residual, write_next);
}

// ---------------- mean aggregation: fp8 gathers, 4 edges/wave x 4-unroll ----------------

__global__ void k_agg(const int* __restrict__ off, const int* __restrict__ ebuf,
                      const float* __restrict__ rden, const unsigned* __restrict__ hb8,
                      ushort* __restrict__ ABh) {
    unsigned* AB = (unsigned*)ABh;          // rows = 64 uints (2 bf16 each)
    int t = threadIdx.x;
    int lane = t & 63;
    int q = lane >> 4;                      // edge slot 0..3
    int fl = lane & 15;                     // feature-word (4 features)
    int w = blockIdx.x * (blockDim.x >> 6) + (t >> 6);
    int nw = gridDim.x * (blockDim.x >> 6);
    for (int n = w; n < NODES; n += nw) {
        int p0 = off[n], p1 = off[n + 1];
        float a0 = 0.f, a1 = 0.f, a2 = 0.f, a3 = 0.f;
        int p = p0 + q;
        for (; p + 12 < p1; p += 16) {
            int s0 = ebuf[p], s1 = ebuf[p + 4], s2 = ebuf[p + 8], s3 = ebuf[p + 12];
            unsigned v0 = hb8[(size_t)s0 * 16 + fl];
            unsigned v1 = hb8[(size_t)s1 * 16 + fl];
            unsigned v2 = hb8[(size_t)s2 * 16 + fl];
            unsigned v3 = hb8[(size_t)s3 * 16 + fl];
            acc4_fp8(v0, a0, a1, a2, a3);
            acc4_fp8(v1, a0, a1, a2, a3);
            acc4_fp8(v2, a0, a1, a2, a3);
            acc4_fp8(v3, a0, a1, a2, a3);
        }
        for (; p < p1; p += 4) {
            unsigned v = hb8[(size_t)ebuf[p] * 16 + fl];
            acc4_fp8(v, a0, a1, a2, a3);
        }
        a0 += __shfl_xor(a0, 16); a0 += __shfl_xor(a0, 32);
        a1 += __shfl_xor(a1, 16); a1 += __shfl_xor(a1, 32);
        a2 += __shfl_xor(a2, 16); a2 += __shfl_xor(a2, 32);
        a3 += __shfl_xor(a3, 16); a3 += __shfl_xor(a3, 32);
        if (q == 0) {
            float rd = rden[n];
            uint2 o;
            o.x = (unsigned)bf16bits(a0 * rd) | ((unsigned)bf16bits(a1 * rd) << 16);
            o.y = (unsigned)bf16bits(a2 * rd) | ((unsigned)bf16bits(a3 * rd) << 16);
            *(uint2*)(AB + (size_t)n * 64 + fl * 2) = o;
        }
    }
}

// ---------------- launch ----------------

extern "C" void kernel_launch(void* const* d_in, const int* in_sizes, int n_in,
                              void* d_out, int out_size, void* d_ws, size_t ws_size,
                              hipStream_t stream) {
    const float* x    = (const float*)d_in[0];
    const int*   ei   = (const int*)d_in[1];
    const float* w_in = (const float*)d_in[2];
    const float* b_in = (const float*)d_in[3];
    const float* bn0g = (const float*)d_in[4];
    const float* bn0b = (const float*)d_in[5];
    const float* wl   = (const float*)d_in[6];
    const float* bl   = (const float*)d_in[7];
    const float* wr   = (const float*)d_in[8];
    const float* bng  = (const float*)d_in[9];
    const float* bnb  = (const float*)d_in[10];
    const int* esrc = ei;
    const int* edst = ei + EDGES;
    float* h = (float*)d_out;

    char* p = (char*)d_ws;
    auto alloc = [&](size_t bytes) {
        char* r = p;
        p += (bytes + 255) & ~size_t(255);
        return r;
    };
    int*      bintot = (int*)alloc((size_t)NBINS * 4);
    float*    stats  = (float*)alloc((size_t)4 * 2048 * 4);
    int2*     cb     = (int2*)alloc((size_t)NBINS * NBLK * 8);
    unsigned* bbuf   = (unsigned*)alloc((size_t)NBLK * EPB * 4);
    int*      off    = (int*)alloc((size_t)(NODES + 1) * 4);
    float*    rden   = (float*)alloc((size_t)NODES * 4);
    int*      ebuf   = (int*)alloc((size_t)EDGES * 4);
    ushort*   WiT    = (ushort*)alloc(64 * 32 * 2);
    ushort*   WcatT  = (ushort*)alloc(LAYERS * 64 * 128 * 2);
    ushort*   tb     = (ushort*)alloc((size_t)NODES * 64 * 2);
    ushort*   AB     = (ushort*)alloc((size_t)NODES * 128 * 2);
    unsigned* hb8    = (unsigned*)alloc((size_t)NODES * 16 * 4);

    k_prep<<<128, TPB, 0, stream>>>(w_in, wl, wr, WiT, WcatT, bintot, stats);
    k_sort_g0<<<NBLK + G0TILES, 1024, 0, stream>>>(esrc, edst, cb, bintot, bbuf,
                                                   x, WiT, b_in, tb, stats);
    k_csr_bn0<<<NBINS + APPLY_BLOCKS, TPB, 0, stream>>>(cb, bintot, bbuf, off, rden, ebuf,
                                                        tb, stats, bn0g, bn0b, h, AB, hb8);

    for (int l = 0; l < LAYERS; ++l) {
        k_agg<<<2048, TPB, 0, stream>>>(off, ebuf, rden, hb8, AB);
        k_gemm<<<NTILES, TPB, 0, stream>>>(AB, WcatT + l * 8192, bl + l * 64,
                                           tb, stats + (l + 1) * 2048);
        k_apply<<<APPLY_BLOCKS, TPB, 0, stream>>>(tb, stats + (l + 1) * 2048, bng + l * 64,
                                                  bnb + l * 64, h, AB, hb8, 1,
                                                  l < LAYERS - 1 ? 1 : 0);
    }
}

// Round 11
// 261.067 us; speedup vs baseline: 4.8627x; 1.0689x over previous
//
#include <hip/hip_runtime.h>
#include <hip/hip_bf16.h>

#define NODES 50000
#define EDGES 800000
#define DIN   19
#define LAYERS 3
#define BN_EPS 1e-5f

#define NBINS 196          // ceil(NODES/256), bin = dst>>8
#define EPB   4096         // edges per sort chunk
#define NBLK  196          // ceil(EDGES/EPB)
#define NTILES 782         // ceil(NODES/64)
#define G0TILES 196        // gemm0: 256-row tiles
#define TPB   256

typedef __attribute__((ext_vector_type(4))) float f32x4;
typedef __attribute__((ext_vector_type(2))) float f32x2;
typedef __attribute__((ext_vector_type(8))) short s16x8;

__device__ inline ushort bf16bits(float f) {
    __hip_bfloat16 h = __float2bfloat16(f);
    return *reinterpret_cast<ushort*>(&h);
}
__device__ inline float bf16val(ushort u) { return __uint_as_float((unsigned)u << 16); }

// ---------- fp8 pack/unpack (e4m3 via HW cvt; e5m2-from-f16 fallback, header-free) ----------
#if __has_builtin(__builtin_amdgcn_cvt_pk_f32_fp8) && __has_builtin(__builtin_amdgcn_cvt_pk_fp8_f32)
__device__ inline unsigned pack4_fp8(float a, float b, float c, float d) {
    unsigned w = __builtin_amdgcn_cvt_pk_fp8_f32(a, b, 0u, false);
    return __builtin_amdgcn_cvt_pk_fp8_f32(c, d, w, true);
}
__device__ inline void acc4_fp8(unsigned v, float* a) {
    f32x2 lo = __builtin_amdgcn_cvt_pk_f32_fp8(v, false);
    f32x2 hi = __builtin_amdgcn_cvt_pk_f32_fp8(v, true);
    a[0] += lo.x; a[1] += lo.y; a[2] += hi.x; a[3] += hi.y;
}
#else
__device__ inline unsigned enc1(float f) {            // e5m2 = top byte of fp16, RN
    _Float16 hf = (_Float16)f;
    unsigned u = (unsigned)*reinterpret_cast<unsigned short*>(&hf);
    u = (u + 0x7Fu + ((u >> 8) & 1u)) >> 8;
    return u & 0xFFu;
}
__device__ inline float dec1(unsigned b) {
    unsigned short u = (unsigned short)(b << 8);
    _Float16 hf = *reinterpret_cast<_Float16*>(&u);
    return (float)hf;
}
__device__ inline unsigned pack4_fp8(float a, float b, float c, float d) {
    return enc1(a) | (enc1(b) << 8) | (enc1(c) << 16) | (enc1(d) << 24);
}
__device__ inline void acc4_fp8(unsigned v, float* a) {
    a[0] += dec1(v & 0xFF); a[1] += dec1((v >> 8) & 0xFF);
    a[2] += dec1((v >> 16) & 0xFF); a[3] += dec1(v >> 24);
}
#endif

// ---------------- k_prep: zero bintot/stats, build transposed bf16 weights ----------------

__global__ void k_prep(const float* __restrict__ w_in, const float* __restrict__ wl,
                       const float* __restrict__ wr, ushort* __restrict__ WiT,
                       ushort* __restrict__ WcatT, int* __restrict__ bintot,
                       float* __restrict__ stats) {
    int i0 = blockIdx.x * blockDim.x + threadIdx.x;
    int stride = gridDim.x * blockDim.x;
    for (int i = i0; i < NBINS; i += stride) bintot[i] = 0;
    for (int i = i0; i < 4 * 2048; i += stride) stats[i] = 0.0f;
    for (int i = i0; i < 64 * 32; i += stride) {
        int c = i >> 5, k = i & 31;
        WiT[i] = bf16bits(k < DIN ? w_in[k * 64 + c] : 0.0f);
    }
    for (int i = i0; i < LAYERS * 64 * 128; i += stride) {
        int l = i >> 13, rem = i & 8191;
        int c = rem >> 7, k = rem & 127;
        float v = (k < 64) ? wl[(l * 64 + k) * 64 + c] : wr[(l * 64 + (k - 64)) * 64 + c];
        WcatT[i] = bf16bits(v);
    }
}

// ================= K2: edge counting-sort (blocks 0..NBLK-1)  ∥  input-proj GEMM =================

union SMemK2 {
    struct { int hist[256], cur[256], wsum[4]; unsigned stage[EPB]; } sort;
    struct { ushort xt[256][40]; float red[4][4][128]; } g0;
};

__device__ inline void do_sortA(int blk, int t, const int* __restrict__ src,
                                const int* __restrict__ dst, int2* __restrict__ cb,
                                int* __restrict__ bintot, unsigned* __restrict__ bbuf,
                                SMemK2& sm) {
    int e0 = blk * EPB;
    int ne = min(EPB, EDGES - e0);
    int d[4]; unsigned pk[4];
    #pragma unroll
    for (int i = 0; i < 4; ++i) {
        int j = t + i * 1024;
        if (j < ne) {
            int dd = dst[e0 + j];
            d[i] = dd;
            pk[i] = ((unsigned)(dd & 255) << 24) | (unsigned)src[e0 + j];
        } else d[i] = -1;
    }
    if (t < 256) sm.sort.hist[t] = 0;
    __syncthreads();
    #pragma unroll
    for (int i = 0; i < 4; ++i)
        if (d[i] >= 0) atomicAdd(&sm.sort.hist[d[i] >> 8], 1);
    __syncthreads();
    int ln = t & 63, wv = t >> 6;
    int cntv = 0, inc = 0;
    if (t < 256) {
        cntv = sm.sort.hist[t];
        inc = cntv;
        #pragma unroll
        for (int s = 1; s < 64; s <<= 1) {
            int u = __shfl_up(inc, s);
            if (ln >= s) inc += u;
        }
        if (ln == 63) sm.sort.wsum[wv] = inc;
    }
    __syncthreads();
    if (t < 256) {
        int woff = 0;
        #pragma unroll
        for (int i = 0; i < 4; ++i) if (i < wv) woff += sm.sort.wsum[i];
        int excl = woff + inc - cntv;
        sm.sort.cur[t] = excl;
        if (t < NBINS) {
            cb[t * NBLK + blk] = make_int2(excl, cntv);
            if (cntv) atomicAdd(&bintot[t], cntv);
        }
    }
    __syncthreads();
    #pragma unroll
    for (int i = 0; i < 4; ++i)
        if (d[i] >= 0) {
            int slot = atomicAdd(&sm.sort.cur[d[i] >> 8], 1);
            sm.sort.stage[slot] = pk[i];
        }
    __syncthreads();
    #pragma unroll
    for (int i = 0; i < 4; ++i) {
        int j = t + i * 1024;
        if (j < ne) bbuf[e0 + j] = sm.sort.stage[j];
    }
}

__device__ inline void do_gemm0(int tile, int t, const float* __restrict__ x,
                                const ushort* __restrict__ WiT, const float* __restrict__ bias,
                                ushort* __restrict__ tb, float* __restrict__ stats,
                                SMemK2& sm) {
    int base = tile * 256;
    int nv = min(256, NODES - base);
    unsigned* xz = (unsigned*)sm.g0.xt;
    for (int i = t; i < 256 * 20; i += 1024) xz[i] = 0;
    __syncthreads();
    const float* xs = x + (size_t)base * DIN;
    for (int e = t; e < nv * DIN; e += 1024) {
        int n = e / DIN, k = e - n * DIN;
        sm.g0.xt[n][k] = bf16bits(xs[e]);
    }
    __syncthreads();
    int grp = t >> 8, tl = t & 255;
    int lane = t & 63, wl = (tl >> 6);
    int r = lane & 15, g = lane >> 4;
    f32x4 acc[4] = {{0.f,0.f,0.f,0.f},{0.f,0.f,0.f,0.f},{0.f,0.f,0.f,0.f},{0.f,0.f,0.f,0.f}};
    s16x8 af = *(const s16x8*)&sm.g0.xt[grp * 64 + wl * 16 + r][g * 8];
    #pragma unroll
    for (int j = 0; j < 4; ++j) {
        s16x8 bf = *(const s16x8*)(WiT + (size_t)(j * 16 + r) * 32 + g * 8);
        acc[j] = __builtin_amdgcn_mfma_f32_16x16x32_bf16(af, bf, acc[j], 0, 0, 0);
    }
    int row0 = base + grp * 64 + wl * 16;
    float s_[4], q_[4];
    #pragma unroll
    for (int j = 0; j < 4; ++j) {
        float b = bias[j * 16 + r];
        float s = 0.0f, q = 0.0f;
        #pragma unroll
        for (int i = 0; i < 4; ++i) {
            int row = row0 + g * 4 + i;
            if (row < NODES) {
                float v = acc[j][i] + b;
                tb[(size_t)row * 64 + j * 16 + r] = bf16bits(v);
                s += v; q += v * v;
            }
        }
        s += __shfl_xor(s, 16); s += __shfl_xor(s, 32);
        q += __shfl_xor(q, 16); q += __shfl_xor(q, 32);
        s_[j] = s; q_[j] = q;
    }
    if (g == 0) {
        #pragma unroll
        for (int j = 0; j < 4; ++j) {
            sm.g0.red[grp][wl][j * 16 + r] = s_[j];
            sm.g0.red[grp][wl][64 + j * 16 + r] = q_[j];
        }
    }
    __syncthreads();
    if (tl < 128) {
        float tot = sm.g0.red[grp][0][tl] + sm.g0.red[grp][1][tl] +
                    sm.g0.red[grp][2][tl] + sm.g0.red[grp][3][tl];
        atomicAdd(&stats[tl * 16], tot);
    }
}

__global__ __launch_bounds__(1024) void k_sort_g0(const int* __restrict__ esrc, const int* __restrict__ edst,
                                                  int2* __restrict__ cb, int* __restrict__ bintot,
                                                  unsigned* __restrict__ bbuf,
                                                  const float* __restrict__ x, const ushort* __restrict__ WiT,
                                                  const float* __restrict__ bias, ushort* __restrict__ tb,
                                                  float* __restrict__ stats) {
    __shared__ SMemK2 sm;
    int t = threadIdx.x;
    if (blockIdx.x < NBLK) do_sortA(blockIdx.x, t, esrc, edst, cb, bintot, bbuf, sm);
    else                   do_gemm0(blockIdx.x - NBLK, t, x, WiT, bias, tb, stats, sm);
}

// ================= apply (BN+ReLU+residual) fused with gemmR (h_tile @ wr + bl -> tb2) =========

struct SMemApplyR {
    ushort hn[64][72];      // padded: bank-free b128 reads
};

__device__ inline void do_applyR(int rb, int t, int l,
                                 const ushort* __restrict__ tb, const float* __restrict__ stats,
                                 const float* __restrict__ gamma, const float* __restrict__ beta,
                                 float* __restrict__ h, unsigned* __restrict__ hb8,
                                 const ushort* __restrict__ WcatT, const float* __restrict__ bl,
                                 ushort* __restrict__ tb2, int residual, SMemApplyR& sm) {
    const float invN = 1.0f / NODES;
    int base = rb * 64;
    int nv = min(64, NODES - base);
    for (int idx = t; idx < nv * 16; idx += TPB) {
        int n = base + (idx >> 4);
        int j = (idx & 15) * 4;
        ushort4 tv = *(const ushort4*)(tb + (size_t)n * 64 + j);
        float tf[4] = { bf16val(tv.x), bf16val(tv.y), bf16val(tv.z), bf16val(tv.w) };
        f32x4 hv;
        if (residual) hv = *(const f32x4*)(h + (size_t)n * 64 + j);
        float out[4];
        #pragma unroll
        for (int k = 0; k < 4; ++k) {
            int f = j + k;
            float mu = stats[f * 16] * invN;
            float var = stats[(64 + f) * 16] * invN - mu * mu;
            float sc = gamma[f] * rsqrtf(var + BN_EPS);
            float sh = beta[f] - mu * sc;
            float v = fmaxf(tf[k] * sc + sh, 0.0f);
            out[k] = residual ? (hv[k] + v) : v;
            sm.hn[idx >> 4][j + k] = bf16bits(out[k]);
        }
        *(f32x4*)(h + (size_t)n * 64 + j) = f32x4{out[0], out[1], out[2], out[3]};
        hb8[(size_t)n * 16 + (idx & 15)] = pack4_fp8(out[0], out[1], out[2], out[3]);
    }
    __syncthreads();
    // gemmR: t2 = hn @ wr[l] + bl[l]   (K=64, right half of WcatT)
    int lane = t & 63, wave = t >> 6;
    int r = lane & 15, g = lane >> 4;
    f32x4 acc[4] = {{0.f,0.f,0.f,0.f},{0.f,0.f,0.f,0.f},{0.f,0.f,0.f,0.f},{0.f,0.f,0.f,0.f}};
    #pragma unroll
    for (int k0 = 0; k0 < 64; k0 += 32) {
        s16x8 af = *(const s16x8*)&sm.hn[wave * 16 + r][k0 + g * 8];
        #pragma unroll
        for (int j = 0; j < 4; ++j) {
            s16x8 bf = *(const s16x8*)(WcatT + (size_t)l * 8192 + (size_t)(j * 16 + r) * 128 + 64 + k0 + g * 8);
            acc[j] = __builtin_amdgcn_mfma_f32_16x16x32_bf16(af, bf, acc[j], 0, 0, 0);
        }
    }
    #pragma unroll
    for (int j = 0; j < 4; ++j) {
        float b = bl[j * 16 + r];
        #pragma unroll
        for (int i = 0; i < 4; ++i) {
            int row = base + wave * 16 + g * 4 + i;
            if (row < NODES) tb2[(size_t)row * 64 + j * 16 + r] = bf16bits(acc[j][i] + b);
        }
    }
}

__global__ __launch_bounds__(TPB) void k_applyR(const ushort* __restrict__ tb, const float* __restrict__ stats,
                                                const float* __restrict__ gamma, const float* __restrict__ beta,
                                                float* __restrict__ h, unsigned* __restrict__ hb8,
                                                const ushort* __restrict__ WcatT, const float* __restrict__ bl,
                                                ushort* __restrict__ tb2, int l, int residual) {
    __shared__ SMemApplyR sm;
    do_applyR(blockIdx.x, threadIdx.x, l, tb, stats, gamma, beta, h, hb8, WcatT, bl, tb2, residual, sm);
}

// ================= K3: CSR assembly (blocks 0..NBINS-1) ∥ applyR layer 0 =================

__device__ inline int ubound(const int* pre, int f) {
    int lo = 0, hi = NBLK;
    while (lo + 1 < hi) {
        int mid = (lo + hi) >> 1;
        if (pre[mid] <= f) lo = mid; else hi = mid;
    }
    return lo;
}

struct SMemBinB {
    int red[256];
    int segoff[NBLK], segcnt[NBLK], pre[NBLK + 1];
    int deg[256], loff[256], cur[256];
    int wsum4[4];
};

union SMemK3 {
    SMemBinB binb;
    SMemApplyR ar;
};

__device__ inline void do_binB(int b, int t, const int2* __restrict__ cb,
                               const int* __restrict__ bintot, const unsigned* __restrict__ bbuf,
                               int* __restrict__ off, float* __restrict__ rden,
                               int* __restrict__ ebuf, SMemBinB& sm) {
    int ln = t & 63, wv = t >> 6;
    sm.red[t] = (t < b) ? bintot[t] : 0;
    __syncthreads();
    #pragma unroll
    for (int s = 128; s > 0; s >>= 1) {
        if (t < s) sm.red[t] += sm.red[t + s];
        __syncthreads();
    }
    int binoff = sm.red[0];
    if (t < NBLK) {
        int2 c = cb[b * NBLK + t];
        sm.segoff[t] = c.x; sm.segcnt[t] = c.y;
    }
    sm.deg[t] = 0; sm.cur[t] = 0;
    __syncthreads();
    if (wv == 0) {
        int carry = 0;
        for (int base = 0; base < NBLK; base += 64) {
            int idx = base + ln;
            int v = (idx < NBLK) ? sm.segcnt[idx] : 0;
            int inc = v;
            #pragma unroll
            for (int s = 1; s < 64; s <<= 1) {
                int u = __shfl_up(inc, s);
                if (ln >= s) inc += u;
            }
            if (idx < NBLK) sm.pre[idx] = carry + inc - v;
            carry += __shfl(inc, 63);
        }
        if (ln == 0) sm.pre[NBLK] = carry;
    }
    __syncthreads();
    int total = sm.pre[NBLK];
    for (int f = t; f < total; f += TPB) {
        int sg = ubound(sm.pre, f);
        unsigned e = bbuf[sg * EPB + sm.segoff[sg] + (f - sm.pre[sg])];
        atomicAdd(&sm.deg[e >> 24], 1);
    }
    __syncthreads();
    int dv = sm.deg[t], inc2 = dv;
    #pragma unroll
    for (int s = 1; s < 64; s <<= 1) {
        int u = __shfl_up(inc2, s);
        if (ln >= s) inc2 += u;
    }
    if (ln == 63) sm.wsum4[wv] = inc2;
    __syncthreads();
    int woff = 0;
    #pragma unroll
    for (int i = 0; i < 4; ++i) if (i < wv) woff += sm.wsum4[i];
    int excl = woff + inc2 - dv;
    sm.loff[t] = excl;
    int node = (b << 8) + t;
    if (node < NODES) {
        off[node] = binoff + excl;
        rden[node] = 1.0f / fmaxf((float)dv, 1.0f);
    }
    if (b == NBINS - 1 && t == 0) off[NODES] = EDGES;
    __syncthreads();
    for (int f = t; f < total; f += TPB) {
        int sg = ubound(sm.pre, f);
        unsigned e = bbuf[sg * EPB + sm.segoff[sg] + (f - sm.pre[sg])];
        int dd = e >> 24;
        int slot = atomicAdd(&sm.cur[dd], 1);
        ebuf[binoff + sm.loff[dd] + slot] = (int)(e & 0xFFFFFFu);
    }
}

__global__ __launch_bounds__(TPB) void k_csr_ar0(const int2* __restrict__ cb, const int* __restrict__ bintot,
                                                 const unsigned* __restrict__ bbuf,
                                                 int* __restrict__ off, float* __restrict__ rden,
                                                 int* __restrict__ ebuf,
                                                 const ushort* __restrict__ tb, const float* __restrict__ stats,
                                                 const float* __restrict__ gamma, const float* __restrict__ beta,
                                                 float* __restrict__ h, unsigned* __restrict__ hb8,
                                                 const ushort* __restrict__ WcatT, const float* __restrict__ bl,
                                                 ushort* __restrict__ tb2) {
    __shared__ SMemK3 sm;
    int t = threadIdx.x;
    if (blockIdx.x < NBINS)
        do_binB(blockIdx.x, t, cb, bintot, bbuf, off, rden, ebuf, sm.binb);
    else
        do_applyR(blockIdx.x - NBINS, t, 0, tb, stats, gamma, beta, h, hb8, WcatT, bl, tb2, 0, sm.ar);
}

// ---------------- gemmL: t = tb2 + agg @ wl[l]  (K=64), + BN stats ----------------

__global__ __launch_bounds__(TPB) void k_gemmL(const ushort* __restrict__ AB, const ushort* __restrict__ WcatT,
                                               const ushort* __restrict__ tb2, ushort* __restrict__ tb,
                                               float* __restrict__ stats, int l) {
    __shared__ float red[4][128];
    int t = threadIdx.x;
    int lane = t & 63, wave = t >> 6;
    int row0 = blockIdx.x * 64;
    int r = lane & 15, g = lane >> 4;
    f32x4 acc[4] = {{0.f,0.f,0.f,0.f},{0.f,0.f,0.f,0.f},{0.f,0.f,0.f,0.f},{0.f,0.f,0.f,0.f}};
    int ar = row0 + wave * 16 + r;
    if (ar >= NODES) ar = NODES - 1;
    #pragma unroll
    for (int k0 = 0; k0 < 64; k0 += 32) {
        s16x8 af = *(const s16x8*)(AB + (size_t)ar * 64 + k0 + g * 8);
        #pragma unroll
        for (int j = 0; j < 4; ++j) {
            s16x8 bf = *(const s16x8*)(WcatT + (size_t)l * 8192 + (size_t)(j * 16 + r) * 128 + k0 + g * 8);
            acc[j] = __builtin_amdgcn_mfma_f32_16x16x32_bf16(af, bf, acc[j], 0, 0, 0);
        }
    }
    float s_[4], q_[4];
    #pragma unroll
    for (int j = 0; j < 4; ++j) {
        float s = 0.0f, q = 0.0f;
        #pragma unroll
        for (int i = 0; i < 4; ++i) {
            int row = row0 + wave * 16 + g * 4 + i;
            if (row < NODES) {
                float v = acc[j][i] + bf16val(tb2[(size_t)row * 64 + j * 16 + r]);
                tb[(size_t)row * 64 + j * 16 + r] = bf16bits(v);
                s += v; q += v * v;
            }
        }
        s += __shfl_xor(s, 16); s += __shfl_xor(s, 32);
        q += __shfl_xor(q, 16); q += __shfl_xor(q, 32);
        s_[j] = s; q_[j] = q;
    }
    if (g == 0) {
        #pragma unroll
        for (int j = 0; j < 4; ++j) {
            red[wave][j * 16 + r] = s_[j];
            red[wave][64 + j * 16 + r] = q_[j];
        }
    }
    __syncthreads();
    if (t < 128) {
        float tot = red[0][t] + red[1][t] + red[2][t] + red[3][t];
        atomicAdd(&stats[t * 16], tot);
    }
}

// ---------------- final apply: BN + ReLU + residual, h only ----------------

__global__ void k_apply_fin(const ushort* __restrict__ tb, const float* __restrict__ stats,
                            const float* __restrict__ gamma, const float* __restrict__ beta,
                            float* __restrict__ h) {
    int idx0 = blockIdx.x * blockDim.x + threadIdx.x;
    int stride = gridDim.x * blockDim.x;
    const float invN = 1.0f / NODES;
    for (int idx = idx0; idx < NODES * 16; idx += stride) {
        int n = idx >> 4;
        int j = (idx & 15) * 4;
        ushort4 tv = *(const ushort4*)(tb + (size_t)n * 64 + j);
        float tf[4] = { bf16val(tv.x), bf16val(tv.y), bf16val(tv.z), bf16val(tv.w) };
        f32x4 hv = *(const f32x4*)(h + (size_t)n * 64 + j);
        float out[4];
        #pragma unroll
        for (int k = 0; k < 4; ++k) {
            int f = j + k;
            float mu = stats[f * 16] * invN;
            float var = stats[(64 + f) * 16] * invN - mu * mu;
            float sc = gamma[f] * rsqrtf(var + BN_EPS);
            float sh = beta[f] - mu * sc;
            out[k] = hv[k] + fmaxf(tf[k] * sc + sh, 0.0f);
        }
        *(f32x4*)(h + (size_t)n * 64 + j) = f32x4{out[0], out[1], out[2], out[3]};
    }
}

// ---------------- mean aggregation: fp8 uint2 gathers, 8 slots/wave x 2-unroll ----------------

__global__ void k_agg(const int* __restrict__ off, const int* __restrict__ ebuf,
                      const float* __restrict__ rden, const unsigned* __restrict__ hb8,
                      ushort* __restrict__ ABh) {
    const uint2* H2 = (const uint2*)hb8;     // row = 8 uint2 (64 fp8)
    uint4* AB4 = (uint4*)ABh;                // row = 8 uint4 (64 bf16)
    int t = threadIdx.x;
    int lane = t & 63;
    int q = lane >> 3;                       // edge slot 0..7
    int fl = lane & 7;                       // uint2 index within row (8 features)
    int w = blockIdx.x * (blockDim.x >> 6) + (t >> 6);
    int nw = gridDim.x * (blockDim.x >> 6);
    for (int n = w; n < NODES; n += nw) {
        int p0 = off[n], p1 = off[n + 1];
        float a[8] = {0.f,0.f,0.f,0.f,0.f,0.f,0.f,0.f};
        int p = p0 + q;
        for (; p + 8 < p1; p += 16) {
            int s0 = ebuf[p], s1 = ebuf[p + 8];
            uint2 v0 = H2[(size_t)s0 * 8 + fl];
            uint2 v1 = H2[(size_t)s1 * 8 + fl];
            acc4_fp8(v0.x, a); acc4_fp8(v0.y, a + 4);
            acc4_fp8(v1.x, a); acc4_fp8(v1.y, a + 4);
        }
        for (; p < p1; p += 8) {
            uint2 v = H2[(size_t)ebuf[p] * 8 + fl];
            acc4_fp8(v.x, a); acc4_fp8(v.y, a + 4);
        }
        #pragma unroll
        for (int i = 0; i < 8; ++i) {
            a[i] += __shfl_xor(a[i], 8);
            a[i] += __shfl_xor(a[i], 16);
            a[i] += __shfl_xor(a[i], 32);
        }
        if (q == 0) {
            float rd = rden[n];
            uint4 o;
            o.x = (unsigned)bf16bits(a[0] * rd) | ((unsigned)bf16bits(a[1] * rd) << 16);
            o.y = (unsigned)bf16bits(a[2] * rd) | ((unsigned)bf16bits(a[3] * rd) << 16);
            o.z = (unsigned)bf16bits(a[4] * rd) | ((unsigned)bf16bits(a[5] * rd) << 16);
            o.w = (unsigned)bf16bits(a[6] * rd) | ((unsigned)bf16bits(a[7] * rd) << 16);
            AB4[(size_t)n * 8 + fl] = o;
        }
    }
}

// ---------------- launch ----------------

extern "C" void kernel_launch(void* const* d_in, const int* in_sizes, int n_in,
                              void* d_out, int out_size, void* d_ws, size_t ws_size,
                              hipStream_t stream) {
    const float* x    = (const float*)d_in[0];
    const int*   ei   = (const int*)d_in[1];
    const float* w_in = (const float*)d_in[2];
    const float* b_in = (const float*)d_in[3];
    const float* bn0g = (const float*)d_in[4];
    const float* bn0b = (const float*)d_in[5];
    const float* wl   = (const float*)d_in[6];
    const float* bl   = (const float*)d_in[7];
    const float* wr   = (const float*)d_in[8];
    const float* bng  = (const float*)d_in[9];
    const float* bnb  = (const float*)d_in[10];
    const int* esrc = ei;
    const int* edst = ei + EDGES;
    float* h = (float*)d_out;

    char* p = (char*)d_ws;
    auto alloc = [&](size_t bytes) {
        char* r = p;
        p += (bytes + 255) & ~size_t(255);
        return r;
    };
    int*      bintot = (int*)alloc((size_t)NBINS * 4);
    float*    stats  = (float*)alloc((size_t)4 * 2048 * 4);
    int2*     cb     = (int2*)alloc((size_t)NBINS * NBLK * 8);
    unsigned* bbuf   = (unsigned*)alloc((size_t)NBLK * EPB * 4);
    int*      off    = (int*)alloc((size_t)(NODES + 1) * 4);
    float*    rden   = (float*)alloc((size_t)NODES * 4);
    int*      ebuf   = (int*)alloc((size_t)EDGES * 4);
    ushort*   WiT    = (ushort*)alloc(64 * 32 * 2);
    ushort*   WcatT  = (ushort*)alloc(LAYERS * 64 * 128 * 2);
    ushort*   tb     = (ushort*)alloc((size_t)NODES * 64 * 2);
    ushort*   tb2    = (ushort*)alloc((size_t)NODES * 64 * 2);
    ushort*   AB     = (ushort*)alloc((size_t)NODES * 64 * 2);
    unsigned* hb8    = (unsigned*)alloc((size_t)NODES * 16 * 4);

    k_prep<<<128, TPB, 0, stream>>>(w_in, wl, wr, WiT, WcatT, bintot, stats);
    k_sort_g0<<<NBLK + G0TILES, 1024, 0, stream>>>(esrc, edst, cb, bintot, bbuf,
                                                   x, WiT, b_in, tb, stats);
    // CSR assembly ∥ (apply0 + gemmR layer 0)
    k_csr_ar0<<<NBINS + NTILES, TPB, 0, stream>>>(cb, bintot, bbuf, off, rden, ebuf,
                                                  tb, stats, bn0g, bn0b, h, hb8,
                                                  WcatT, bl + 0 * 64, tb2);

    for (int l = 0; l < LAYERS; ++l) {
        k_agg<<<2048, TPB, 0, stream>>>(off, ebuf, rden, hb8, AB);
        k_gemmL<<<NTILES, TPB, 0, stream>>>(AB, WcatT, tb2, tb, stats + (l + 1) * 2048, l);
        if (l < LAYERS - 1) {
            k_applyR<<<NTILES, TPB, 0, stream>>>(tb, stats + (l + 1) * 2048, bng + l * 64,
                                                 bnb + l * 64, h, hb8, WcatT,
                                                 bl + (l + 1) * 64, tb2, l + 1, 1);
        } else {
            k_apply_fin<<<2048, TPB, 0, stream>>>(tb, stats + (l + 1) * 2048, bng + l * 64,
                                                  bnb + l * 64, h);
        }
    }
}